// Round 14
// baseline (252.965 us; speedup 1.0000x reference)
//
#include <hip/hip_runtime.h>
#include <hip/hip_bf16.h>

#define NGRAPH 64
#define NGENES 16000
#define NANNOT 8000
#define NNODES 10000
#define NTOT   (NGRAPH * NNODES)
#define DEG    4
#define NEDGE  (NGRAPH * NNODES * DEG)
#define KSEL   5000
#define FIXS   1048576.0f

#define KSPLIT 2
#define KSTEP  160
#define KSTEPS (NGENES / KSPLIT / KSTEP)   // 50
#define LDSROW 164                         // 160 + 4 pad ushorts (328 B row)
#define NCHUNK 125                         // 16-float4 chunks per half-row (8000/64)

typedef __attribute__((ext_vector_type(8))) short bf16x8;
typedef __attribute__((ext_vector_type(4))) float f32x4;

__device__ __forceinline__ unsigned short f2bf(float x) {
  __hip_bfloat16 h = __float2bfloat16(x);   // RN
  return __builtin_bit_cast(unsigned short, h);
}
__device__ __forceinline__ float bf2f(unsigned short u) {
  unsigned int v = (unsigned int)u << 16;
  return __builtin_bit_cast(float, v);
}

// ---------------- kernel B: masked fc1, bf16x2 MFMA, mask-bitmap w-skip -------------
// Pre-pass: stream this block's [64 x 8000] adj tile once -> 1 bit per float4 in LDS.
// Main loop: tr dense; where bit set load BOTH w and adj and multiply per component
// (bit-identical to the dense r12 kernel); where clear, p = 0 exactly.
__global__ __launch_bounds__(256, 1) void fc1_kernel(
    const float* __restrict__ tr, const float* __restrict__ w,
    const float* __restrict__ mk, float* __restrict__ partials) {
  __shared__ unsigned short sAh[2][64 * LDSROW];
  __shared__ unsigned short sBh[2][64 * LDSROW];
  __shared__ unsigned short sBl[2][64 * LDSROW];
  __shared__ unsigned short s_bm[64 * NCHUNK];   // 16 KB bitmask

  const int t = threadIdx.x;
  const int abase = blockIdx.x * 64;                 // 125 * 64 = 8000
  const int kbeg  = blockIdx.y * (NGENES / KSPLIT);  // 0 or 8000
  const int wv = t >> 6, lane = t & 63, lr = lane & 15, ls = lane >> 4;

  const float* wB = w  + (size_t)abase * NGENES;
  const float* aB = mk + (size_t)abase * NGENES;

  // ---- pre-pass: build bitmask (each ushort = 16 consecutive float4s of a row) ----
  for (int u = t; u < 64 * NCHUNK; u += 256) {
    int r = u / NCHUNK, c = u - NCHUNK * r;
    const float4* ap = (const float4*)&aB[(size_t)r * NGENES + kbeg + c * 64];
    unsigned m = 0;
#pragma unroll
    for (int i = 0; i < 16; ++i) {
      float4 v = ap[i];
      if (v.x != 0.f || v.y != 0.f || v.z != 0.f || v.w != 0.f) m |= (1u << i);
    }
    s_bm[u] = (unsigned short)m;
  }

  // staging map: flat 2560 float4 per (array, step); 10 per thread
  int soff[10], loff[10], bmrow[10], c4a[10];
#pragma unroll
  for (int j = 0; j < 10; ++j) {
    int f = t + 256 * j;
    int row = f / 40, c4 = f - 40 * row;
    soff[j] = row * NGENES + c4 * 4;
    loff[j] = row * LDSROW + c4 * 4;
    bmrow[j] = row * NCHUNK;
    c4a[j] = c4;
  }

  float4 rt[10], rw[10], ra[10];

  __syncthreads();   // bitmask ready before any load_step reads it

  auto load_step = [&](int s) {
    const int k0 = kbeg + s * KSTEP;
#pragma unroll
    for (int j = 0; j < 10; ++j) {
      rt[j] = *(const float4*)&tr[soff[j] + k0];
      int ca = 40 * s + c4a[j];
      bool dirty = (s_bm[bmrow[j] + (ca >> 4)] >> (ca & 15)) & 1;
      rw[j] = make_float4(0.f, 0.f, 0.f, 0.f);
      ra[j] = make_float4(0.f, 0.f, 0.f, 0.f);
      if (dirty) {
        rw[j] = *(const float4*)&wB[soff[j] + k0];
        ra[j] = *(const float4*)&aB[soff[j] + k0];
      }
    }
  };
  auto store_step = [&](int buf) {
#pragma unroll
    for (int j = 0; j < 10; ++j) {
      ushort4 ah;
      ah.x = f2bf(rt[j].x); ah.y = f2bf(rt[j].y);
      ah.z = f2bf(rt[j].z); ah.w = f2bf(rt[j].w);
      *(ushort4*)&sAh[buf][loff[j]] = ah;
      float4 p = make_float4(rw[j].x * ra[j].x, rw[j].y * ra[j].y,
                             rw[j].z * ra[j].z, rw[j].w * ra[j].w);
      ushort4 bh, bl;
      bh.x = f2bf(p.x); bl.x = f2bf(p.x - bf2f(bh.x));
      bh.y = f2bf(p.y); bl.y = f2bf(p.y - bf2f(bh.y));
      bh.z = f2bf(p.z); bl.z = f2bf(p.z - bf2f(bh.z));
      bh.w = f2bf(p.w); bl.w = f2bf(p.w - bf2f(bh.w));
      *(ushort4*)&sBh[buf][loff[j]] = bh;
      *(ushort4*)&sBl[buf][loff[j]] = bl;
    }
  };

  f32x4 acc[4];
#pragma unroll
  for (int mt = 0; mt < 4; ++mt)
#pragma unroll
    for (int r = 0; r < 4; ++r) acc[mt][r] = 0.f;

  const int fbA = lr * LDSROW + ls * 8;
  const int fbB = (wv * 16 + lr) * LDSROW + ls * 8;

  auto compute = [&](int buf) {
#pragma unroll
    for (int ks = 0; ks < KSTEP / 32; ++ks) {
      bf16x8 bh = *(const bf16x8*)&sBh[buf][fbB + ks * 32];
      bf16x8 bl = *(const bf16x8*)&sBl[buf][fbB + ks * 32];
#pragma unroll
      for (int mt = 0; mt < 4; ++mt) {
        bf16x8 ah = *(const bf16x8*)&sAh[buf][mt * 16 * LDSROW + fbA + ks * 32];
        acc[mt] = __builtin_amdgcn_mfma_f32_16x16x32_bf16(ah, bh, acc[mt], 0, 0, 0);
        acc[mt] = __builtin_amdgcn_mfma_f32_16x16x32_bf16(ah, bl, acc[mt], 0, 0, 0);
      }
    }
  };

  load_step(0);
  store_step(0);
  load_step(1);
  __syncthreads();

#pragma unroll 1
  for (int s = 0; s < KSTEPS; ++s) {
    const int buf = s & 1;
    compute(buf);
    if (s + 1 < KSTEPS) {
      store_step(buf ^ 1);
      if (s + 2 < KSTEPS) load_step(s + 2);
    }
    __syncthreads();
  }

  // epilogue: D col = lane&15, row = (lane>>4)*4 + reg   [m89-verified]
  float* P = partials + (size_t)blockIdx.y * (64 * NANNOT);
  const int acol = abase + wv * 16 + lr;
#pragma unroll
  for (int mt = 0; mt < 4; ++mt) {
#pragma unroll
    for (int r = 0; r < 4; ++r) {
      int b = mt * 16 + ls * 4 + r;
      P[(size_t)b * NANNOT + acol] = acc[mt][r];
    }
  }
}

// ---------------- kernel B2: finalize xg, float4 (branch uniform per quad) ---------
__global__ void finalize_kernel(const float4* __restrict__ partials4,
                                const float* __restrict__ fc1_b,
                                const float4* __restrict__ x4,
                                float4* __restrict__ xg4) {
  int idx4 = blockIdx.x * blockDim.x + threadIdx.x;
  if (idx4 >= NTOT / 4) return;
  int idx = idx4 * 4;
  int b = idx / NNODES, local = idx - b * NNODES;
  float4 o;
  if (local < NANNOT) {
    int p4 = (b * NANNOT + local) >> 2;
    float4 s0 = partials4[p4];
    float4 s1 = partials4[(64 * NANNOT) / 4 + p4];
    const float4 bb = *(const float4*)&fc1_b[local];
    o = make_float4(bb.x + s0.x + s1.x, bb.y + s0.y + s1.y,
                    bb.z + s0.z + s1.z, bb.w + s0.w + s1.w);
  } else {
    o = x4[idx4];
  }
  xg4[idx4] = o;
}

// ---------------- kernel C1: edge aggregation, 4 blocks/graph, LDS atomics ---------
__global__ __launch_bounds__(1024) void agg_kernel(
    const int* __restrict__ ei, const float* __restrict__ xg,
    int* __restrict__ part_sum, int* __restrict__ part_deg) {
  const int blk = blockIdx.x;          // 0..255
  const int g = blk >> 2, q = blk & 3;
  const int t = threadIdx.x;
  __shared__ int s_sum[NNODES];
  __shared__ int s_deg[NNODES];
  for (int i = t; i < NNODES; i += 1024) { s_sum[i] = 0; s_deg[i] = 0; }
  __syncthreads();

  const int ebase = g * (NNODES * DEG) + q * (NNODES * DEG / 4);
  const int base = g * NNODES;
  const int4* src4 = (const int4*)(ei + ebase);
  const int4* dst4 = (const int4*)(ei + NEDGE + ebase);
  const int nq = (NNODES * DEG / 4) / 4;   // 2500
  for (int v = t; v < nq; v += 1024) {
    int4 s4 = src4[v];
    int4 d4 = dst4[v];
#pragma unroll
    for (int u = 0; u < 4; ++u) {
      int s = (&s4.x)[u];
      int d = (&d4.x)[u];
      float vv = ((unsigned)s < (unsigned)NTOT) ? xg[s] : 0.f;
      unsigned dl = (unsigned)(d - base);
      if (dl < (unsigned)NNODES) {
        atomicAdd(&s_sum[dl], __float2int_rn(vv * FIXS));
        atomicAdd(&s_deg[dl], 1);
      }
    }
  }
  __syncthreads();

  int* ps = part_sum + (size_t)blk * NNODES;
  int* pd = part_deg + (size_t)blk * NNODES;
  for (int i = t; i < NNODES; i += 1024) { ps[i] = s_sum[i]; pd[i] = s_deg[i]; }
}

// ---------------- kernel C2: per-graph h + 2-pass radix select + fc2 ---------------
__global__ __launch_bounds__(1024) void select_kernel(
    const int* __restrict__ part_sum, const int* __restrict__ part_deg,
    const float* __restrict__ xg,
    const float* __restrict__ wrp, const float* __restrict__ wnp,
    const float* __restrict__ pbp, const float* __restrict__ fc2w,
    const float* __restrict__ fc2b, float* __restrict__ out) {
  const int g = blockIdx.x;
  const int t = threadIdx.x;
  const int lane = t & 63, wid = t >> 6;
  __shared__ float s_h[NNODES];
  __shared__ int s_hist[256];
  __shared__ int s_cnt[256];
  __shared__ float s_red[1024];
  __shared__ int s_wsum[16];
  __shared__ int s_wpre[16];
  __shared__ unsigned s_pfx;
  __shared__ int s_rem;

  const int base = g * NNODES;
  const float wr = wrp[0], wn = wnp[0], pb = pbp[0];
  for (int i = t; i < NNODES; i += 1024) {
    int sum = 0, dg = 0;
#pragma unroll
    for (int q = 0; q < 4; ++q) {
      size_t off = (size_t)(g * 4 + q) * NNODES + i;
      sum += part_sum[off];
      dg  += part_deg[off];
    }
    float mean = ((float)sum * (1.0f / FIXS)) / (float)(dg > 0 ? dg : 1);
    s_h[i] = wr * xg[base + i] + wn * mean + pb;
  }
  __syncthreads();

  // 2-pass radix: top-16-bit prefix T; rank-gate prefix-ties (lowest index first)
  unsigned prefix = 0; int rem = KSEL;
#pragma unroll
  for (int pass = 0; pass < 2; ++pass) {
    const int sh = (3 - pass) * 8;
    const unsigned himask = (pass == 0) ? 0u : 0xFF000000u;
    if (t < 256) s_hist[t] = 0;
    __syncthreads();
    for (int i = t; i < NNODES; i += 1024) {
      unsigned kk = __float_as_uint(fabsf(s_h[i]));
      if ((kk & himask) == prefix) atomicAdd(&s_hist[(kk >> sh) & 255], 1);
    }
    __syncthreads();
    if (wid == 0) {
      int h0 = s_hist[4 * lane], h1 = s_hist[4 * lane + 1];
      int h2 = s_hist[4 * lane + 2], h3 = s_hist[4 * lane + 3];
      int lt = h0 + h1 + h2 + h3;
      int sfx = lt;
#pragma unroll
      for (int off = 1; off < 64; off <<= 1) {
        int o = __shfl_down(sfx, off);
        sfx += (lane + off < 64) ? o : 0;
      }
      int above = sfx - lt;
      int ge3 = above + h3;
      int ge2 = ge3 + h2;
      int ge1 = ge2 + h1;
      int ge0 = ge1 + h0;
      s_cnt[4 * lane]     = ge0;
      s_cnt[4 * lane + 1] = ge1;
      s_cnt[4 * lane + 2] = ge2;
      s_cnt[4 * lane + 3] = ge3;
    }
    __syncthreads();
    if (t < 256) {
      int ge = s_cnt[t];
      int ge_next = (t == 255) ? 0 : s_cnt[t + 1];
      if (ge >= rem && ge_next < rem) {
        s_pfx = prefix | ((unsigned)t << sh);
        s_rem = rem - ge_next;
      }
    }
    __syncthreads();
    prefix = s_pfx; rem = s_rem;
    __syncthreads();
  }
  const unsigned T = prefix;
  const int needed = rem;

  const int CH = 10;
  int i0 = t * CH;
  int i1 = i0 + CH; if (i1 > NNODES) i1 = NNODES;
  int loc = 0;
  for (int i = i0; i < i1; ++i)
    loc += ((__float_as_uint(fabsf(s_h[i])) & 0xFFFF0000u) == T) ? 1 : 0;
  int incl = loc;
#pragma unroll
  for (int off = 1; off < 64; off <<= 1) {
    int o = __shfl_up(incl, off);
    if (lane >= off) incl += o;
  }
  if (lane == 63) s_wsum[wid] = incl;
  __syncthreads();
  if (t < 64) {
    int v = (lane < 16) ? s_wsum[lane] : 0;
    int inc16 = v;
#pragma unroll
    for (int off = 1; off < 16; off <<= 1) {
      int o = __shfl_up(inc16, off);
      if (lane >= off) inc16 += o;
    }
    if (lane < 16) s_wpre[lane] = inc16 - v;
  }
  __syncthreads();
  int rank = s_wpre[wid] + (incl - loc);

  float a0 = 0.f, a1 = 0.f;
  for (int i = i0; i < i1; ++i) {
    float h = s_h[i];
    unsigned kp = __float_as_uint(fabsf(h)) & 0xFFFF0000u;
    bool inc = false;
    if (kp > T) inc = true;
    else if (kp == T) { inc = (rank < needed); ++rank; }
    if (inc) {
      a0 += h * fc2w[i];
      a1 += h * fc2w[NNODES + i];
    }
  }
  s_red[t] = a0; __syncthreads();
  for (int off = 512; off > 0; off >>= 1) {
    if (t < off) s_red[t] += s_red[t + off];
    __syncthreads();
  }
  float r0 = s_red[0];
  __syncthreads();
  s_red[t] = a1; __syncthreads();
  for (int off = 512; off > 0; off >>= 1) {
    if (t < off) s_red[t] += s_red[t + off];
    __syncthreads();
  }
  if (t == 0) {
    out[g * 2 + 0] = r0 + fc2b[0];
    out[g * 2 + 1] = s_red[0] + fc2b[1];
  }
}

// ---------------- launch ----------------
extern "C" void kernel_launch(void* const* d_in, const int* in_sizes, int n_in,
                              void* d_out, int out_size, void* d_ws, size_t ws_size,
                              hipStream_t stream) {
  const float* tr  = (const float*)d_in[0];
  const float* x   = (const float*)d_in[1];
  const int*   ei  = (const int*)d_in[2];
  const float* adj = (const float*)d_in[4];
  const float* w1  = (const float*)d_in[5];
  const float* b1  = (const float*)d_in[6];
  const float* wr  = (const float*)d_in[7];
  const float* wn  = (const float*)d_in[8];
  const float* pb  = (const float*)d_in[9];
  const float* w2  = (const float*)d_in[10];
  const float* b2  = (const float*)d_in[11];

  char* ws = (char*)d_ws;
  float* xg       = (float*)ws;                                        // 2.56 MB
  float* partials = (float*)(ws + (size_t)NTOT * 4);                   // 4.10 MB
  int*   part_sum = (int*)(ws + (size_t)NTOT * 4 + (size_t)KSPLIT * 64 * NANNOT * 4);
  int*   part_deg = part_sum + (size_t)4 * NGRAPH * NNODES;            // 10.24 MB each
  float* out = (float*)d_out;

  dim3 g1(NANNOT / 64, KSPLIT);   // 125 x 2 = 250 blocks
  fc1_kernel<<<g1, 256, 0, stream>>>(tr, w1, adj, partials);
  finalize_kernel<<<(NTOT / 4 + 255) / 256, 256, 0, stream>>>(
      (const float4*)partials, b1, (const float4*)x, (float4*)xg);
  agg_kernel<<<4 * NGRAPH, 1024, 0, stream>>>(ei, xg, part_sum, part_deg);
  select_kernel<<<NGRAPH, 1024, 0, stream>>>(part_sum, part_deg, xg, wr, wn, pb, w2, b2, out);
}

// Round 15
// 241.542 us; speedup vs baseline: 1.0473x; 1.0473x over previous
//
#include <hip/hip_runtime.h>
#include <hip/hip_bf16.h>

#define NGRAPH 64
#define NGENES 16000
#define NANNOT 8000
#define NNODES 10000
#define NTOT   (NGRAPH * NNODES)
#define DEG    4
#define NEDGE  (NGRAPH * NNODES * DEG)
#define KSEL   5000
#define FIXS   1048576.0f

#define KSPLIT 2
#define KSTEP  160
#define KSTEPS (NGENES / KSPLIT / KSTEP)   // 50
#define LDSROW 164                         // 160 + 4 pad ushorts (328 B row)

typedef __attribute__((ext_vector_type(8))) short bf16x8;
typedef __attribute__((ext_vector_type(4))) float f32x4;

__device__ __forceinline__ unsigned short f2bf(float x) {
  __hip_bfloat16 h = __float2bfloat16(x);   // RN
  return __builtin_bit_cast(unsigned short, h);
}
__device__ __forceinline__ float bf2f(unsigned short u) {
  unsigned int v = (unsigned int)u << 16;
  return __builtin_bit_cast(float, v);
}

// ---------------- kernel B: masked fc1, bf16x2 MFMA, fused sparse-w pipeline --------
// adj in {0,1} exactly -> p = w*adj == (bit ? w : 0) bitwise. Per tail: compress the
// just-arrived adj step into a 40-bit nibble mask (frees its registers), issue the
// next adj step dense (640B bursts), issue w PREDICATED per-float4 (~4% dirty),
// issue tr. Store selects components by bit. Bit-identical to the dense r12 kernel.
__global__ __launch_bounds__(256, 1) void fc1_kernel(
    const float* __restrict__ tr, const float* __restrict__ w,
    const float* __restrict__ mk, float* __restrict__ partials) {
  __shared__ unsigned short sAh[2][64 * LDSROW];
  __shared__ unsigned short sBh[2][64 * LDSROW];
  __shared__ unsigned short sBl[2][64 * LDSROW];

  const int t = threadIdx.x;
  const int abase = blockIdx.x * 64;                 // 125 * 64 = 8000
  const int kbeg  = blockIdx.y * (NGENES / KSPLIT);  // 0 or 8000
  const int wv = t >> 6, lane = t & 63, lr = lane & 15, ls = lane >> 4;

  int soff[10], loff[10];
#pragma unroll
  for (int j = 0; j < 10; ++j) {
    int f = t + 256 * j;
    int row = f / 40, c4 = f - 40 * row;
    soff[j] = row * NGENES + c4 * 4;
    loff[j] = row * LDSROW + c4 * 4;
  }
  const float* wB = w  + (size_t)abase * NGENES;
  const float* aB = mk + (size_t)abase * NGENES;

  float4 rtA[10], rwA[10] = {}, rtB[10], rwB[10] = {}, ra[10];
  uint2 nibA, nibB;

  auto issue_adj = [&](int s) {
    const int k0 = kbeg + s * KSTEP;
#pragma unroll
    for (int j = 0; j < 10; ++j) ra[j] = *(const float4*)&aB[soff[j] + k0];
  };
  auto compress = [&]() -> uint2 {
    unsigned bx = 0, by = 0;
#pragma unroll
    for (int j = 0; j < 10; ++j) {
      unsigned nb = (ra[j].x != 0.f ? 1u : 0u) | (ra[j].y != 0.f ? 2u : 0u) |
                    (ra[j].z != 0.f ? 4u : 0u) | (ra[j].w != 0.f ? 8u : 0u);
      if (j < 8) bx |= nb << (4 * j);
      else       by |= nb << (4 * (j - 8));
    }
    return make_uint2(bx, by);
  };
  auto nib_of = [&](uint2 nib, int j) -> unsigned {
    return (j < 8) ? ((nib.x >> (4 * j)) & 15u) : ((nib.y >> (4 * (j - 8))) & 15u);
  };
  auto issue_trf = [&](float4* rt, int s) {
    const int k0 = kbeg + s * KSTEP;
#pragma unroll
    for (int j = 0; j < 10; ++j) rt[j] = *(const float4*)&tr[soff[j] + k0];
  };
  auto issue_wf = [&](float4* rw, uint2 nib, int s) {
    const int k0 = kbeg + s * KSTEP;
#pragma unroll
    for (int j = 0; j < 10; ++j)
      if (nib_of(nib, j)) rw[j] = *(const float4*)&wB[soff[j] + k0];
  };
  auto do_store = [&](int buf, float4* rt, float4* rw, uint2 nib) {
#pragma unroll
    for (int j = 0; j < 10; ++j) {
      ushort4 ah;
      ah.x = f2bf(rt[j].x); ah.y = f2bf(rt[j].y);
      ah.z = f2bf(rt[j].z); ah.w = f2bf(rt[j].w);
      *(ushort4*)&sAh[buf][loff[j]] = ah;
      unsigned nb = nib_of(nib, j);
      float4 p;
      p.x = (nb & 1u) ? rw[j].x : 0.f;
      p.y = (nb & 2u) ? rw[j].y : 0.f;
      p.z = (nb & 4u) ? rw[j].z : 0.f;
      p.w = (nb & 8u) ? rw[j].w : 0.f;
      ushort4 bh, bl;
      bh.x = f2bf(p.x); bl.x = f2bf(p.x - bf2f(bh.x));
      bh.y = f2bf(p.y); bl.y = f2bf(p.y - bf2f(bh.y));
      bh.z = f2bf(p.z); bl.z = f2bf(p.z - bf2f(bh.z));
      bh.w = f2bf(p.w); bl.w = f2bf(p.w - bf2f(bh.w));
      *(ushort4*)&sBh[buf][loff[j]] = bh;
      *(ushort4*)&sBl[buf][loff[j]] = bl;
    }
  };

  f32x4 acc[4];
#pragma unroll
  for (int mt = 0; mt < 4; ++mt)
#pragma unroll
    for (int r = 0; r < 4; ++r) acc[mt][r] = 0.f;

  const int fbA = lr * LDSROW + ls * 8;
  const int fbB = (wv * 16 + lr) * LDSROW + ls * 8;

  auto compute = [&](int buf) {
#pragma unroll
    for (int ks = 0; ks < KSTEP / 32; ++ks) {
      bf16x8 bh = *(const bf16x8*)&sBh[buf][fbB + ks * 32];
      bf16x8 bl = *(const bf16x8*)&sBl[buf][fbB + ks * 32];
#pragma unroll
      for (int mt = 0; mt < 4; ++mt) {
        bf16x8 ah = *(const bf16x8*)&sAh[buf][mt * 16 * LDSROW + fbA + ks * 32];
        acc[mt] = __builtin_amdgcn_mfma_f32_16x16x32_bf16(ah, bh, acc[mt], 0, 0, 0);
        acc[mt] = __builtin_amdgcn_mfma_f32_16x16x32_bf16(ah, bl, acc[mt], 0, 0, 0);
      }
    }
  };

  // ---- prologue: establish invariant (nibA = bits[s+1]; ra in flight = adj[s+2]) --
  issue_adj(0);
  nibA = compress();                 // bits[0] (one-time stall on adj0)
  issue_adj(1);
  issue_trf(rtA, 0); issue_wf(rwA, nibA, 0);
  do_store(0, rtA, rwA, nibA);       // step 0 -> buf0
  nibB = compress();                 // bits[1]
  issue_adj(2);
  issue_trf(rtB, 1); issue_wf(rwB, nibB, 1);
  nibA = nibB;                       // nibA = bits[1]
  __syncthreads();

#pragma unroll 1
  for (int sp = 0; sp < 25; ++sp) {
    const int s = 2 * sp;
    compute(0);                      // step s (buf0)
    do_store(1, rtB, rwB, nibA);     // step s+1 -> buf1
    if (s + 2 < KSTEPS) {
      nibB = compress();             // bits[s+2] (adj arrived last tail)
      if (s + 3 < KSTEPS) issue_adj(s + 3);
      issue_wf(rwA, nibB, s + 2);
      issue_trf(rtA, s + 2);
      nibA = nibB;
    }
    __syncthreads();
    compute(1);                      // step s+1 (buf1)
    if (s + 2 < KSTEPS) {
      do_store(0, rtA, rwA, nibA);   // step s+2 -> buf0
      if (s + 3 < KSTEPS) {
        nibB = compress();           // bits[s+3]
        if (s + 4 < KSTEPS) issue_adj(s + 4);
        issue_wf(rwB, nibB, s + 3);
        issue_trf(rtB, s + 3);
        nibA = nibB;
      }
    }
    __syncthreads();
  }

  // epilogue: D col = lane&15, row = (lane>>4)*4 + reg   [m89-verified]
  float* P = partials + (size_t)blockIdx.y * (64 * NANNOT);
  const int acol = abase + wv * 16 + lr;
#pragma unroll
  for (int mt = 0; mt < 4; ++mt) {
#pragma unroll
    for (int r = 0; r < 4; ++r) {
      int b = mt * 16 + ls * 4 + r;
      P[(size_t)b * NANNOT + acol] = acc[mt][r];
    }
  }
}

// ---------------- kernel B2: finalize xg, float4 (branch uniform per quad) ---------
__global__ void finalize_kernel(const float4* __restrict__ partials4,
                                const float* __restrict__ fc1_b,
                                const float4* __restrict__ x4,
                                float4* __restrict__ xg4) {
  int idx4 = blockIdx.x * blockDim.x + threadIdx.x;
  if (idx4 >= NTOT / 4) return;
  int idx = idx4 * 4;
  int b = idx / NNODES, local = idx - b * NNODES;
  float4 o;
  if (local < NANNOT) {
    int p4 = (b * NANNOT + local) >> 2;
    float4 s0 = partials4[p4];
    float4 s1 = partials4[(64 * NANNOT) / 4 + p4];
    const float4 bb = *(const float4*)&fc1_b[local];
    o = make_float4(bb.x + s0.x + s1.x, bb.y + s0.y + s1.y,
                    bb.z + s0.z + s1.z, bb.w + s0.w + s1.w);
  } else {
    o = x4[idx4];
  }
  xg4[idx4] = o;
}

// ---------------- kernel C1: edge aggregation, 4 blocks/graph, LDS atomics ---------
__global__ __launch_bounds__(1024) void agg_kernel(
    const int* __restrict__ ei, const float* __restrict__ xg,
    int* __restrict__ part_sum, int* __restrict__ part_deg) {
  const int blk = blockIdx.x;          // 0..255
  const int g = blk >> 2, q = blk & 3;
  const int t = threadIdx.x;
  __shared__ int s_sum[NNODES];
  __shared__ int s_deg[NNODES];
  for (int i = t; i < NNODES; i += 1024) { s_sum[i] = 0; s_deg[i] = 0; }
  __syncthreads();

  const int ebase = g * (NNODES * DEG) + q * (NNODES * DEG / 4);
  const int base = g * NNODES;
  const int4* src4 = (const int4*)(ei + ebase);
  const int4* dst4 = (const int4*)(ei + NEDGE + ebase);
  const int nq = (NNODES * DEG / 4) / 4;   // 2500
  for (int v = t; v < nq; v += 1024) {
    int4 s4 = src4[v];
    int4 d4 = dst4[v];
#pragma unroll
    for (int u = 0; u < 4; ++u) {
      int s = (&s4.x)[u];
      int d = (&d4.x)[u];
      float vv = ((unsigned)s < (unsigned)NTOT) ? xg[s] : 0.f;
      unsigned dl = (unsigned)(d - base);
      if (dl < (unsigned)NNODES) {
        atomicAdd(&s_sum[dl], __float2int_rn(vv * FIXS));
        atomicAdd(&s_deg[dl], 1);
      }
    }
  }
  __syncthreads();

  int* ps = part_sum + (size_t)blk * NNODES;
  int* pd = part_deg + (size_t)blk * NNODES;
  for (int i = t; i < NNODES; i += 1024) { ps[i] = s_sum[i]; pd[i] = s_deg[i]; }
}

// ---------------- kernel C2: per-graph h + 2-pass radix select + fc2 ---------------
__global__ __launch_bounds__(1024) void select_kernel(
    const int* __restrict__ part_sum, const int* __restrict__ part_deg,
    const float* __restrict__ xg,
    const float* __restrict__ wrp, const float* __restrict__ wnp,
    const float* __restrict__ pbp, const float* __restrict__ fc2w,
    const float* __restrict__ fc2b, float* __restrict__ out) {
  const int g = blockIdx.x;
  const int t = threadIdx.x;
  const int lane = t & 63, wid = t >> 6;
  __shared__ float s_h[NNODES];
  __shared__ int s_hist[256];
  __shared__ int s_cnt[256];
  __shared__ float s_red[1024];
  __shared__ int s_wsum[16];
  __shared__ int s_wpre[16];
  __shared__ unsigned s_pfx;
  __shared__ int s_rem;

  const int base = g * NNODES;
  const float wr = wrp[0], wn = wnp[0], pb = pbp[0];
  for (int i = t; i < NNODES; i += 1024) {
    int sum = 0, dg = 0;
#pragma unroll
    for (int q = 0; q < 4; ++q) {
      size_t off = (size_t)(g * 4 + q) * NNODES + i;
      sum += part_sum[off];
      dg  += part_deg[off];
    }
    float mean = ((float)sum * (1.0f / FIXS)) / (float)(dg > 0 ? dg : 1);
    s_h[i] = wr * xg[base + i] + wn * mean + pb;
  }
  __syncthreads();

  // 2-pass radix: top-16-bit prefix T; rank-gate prefix-ties (lowest index first)
  unsigned prefix = 0; int rem = KSEL;
#pragma unroll
  for (int pass = 0; pass < 2; ++pass) {
    const int sh = (3 - pass) * 8;
    const unsigned himask = (pass == 0) ? 0u : 0xFF000000u;
    if (t < 256) s_hist[t] = 0;
    __syncthreads();
    for (int i = t; i < NNODES; i += 1024) {
      unsigned kk = __float_as_uint(fabsf(s_h[i]));
      if ((kk & himask) == prefix) atomicAdd(&s_hist[(kk >> sh) & 255], 1);
    }
    __syncthreads();
    if (wid == 0) {
      int h0 = s_hist[4 * lane], h1 = s_hist[4 * lane + 1];
      int h2 = s_hist[4 * lane + 2], h3 = s_hist[4 * lane + 3];
      int lt = h0 + h1 + h2 + h3;
      int sfx = lt;
#pragma unroll
      for (int off = 1; off < 64; off <<= 1) {
        int o = __shfl_down(sfx, off);
        sfx += (lane + off < 64) ? o : 0;
      }
      int above = sfx - lt;
      int ge3 = above + h3;
      int ge2 = ge3 + h2;
      int ge1 = ge2 + h1;
      int ge0 = ge1 + h0;
      s_cnt[4 * lane]     = ge0;
      s_cnt[4 * lane + 1] = ge1;
      s_cnt[4 * lane + 2] = ge2;
      s_cnt[4 * lane + 3] = ge3;
    }
    __syncthreads();
    if (t < 256) {
      int ge = s_cnt[t];
      int ge_next = (t == 255) ? 0 : s_cnt[t + 1];
      if (ge >= rem && ge_next < rem) {
        s_pfx = prefix | ((unsigned)t << sh);
        s_rem = rem - ge_next;
      }
    }
    __syncthreads();
    prefix = s_pfx; rem = s_rem;
    __syncthreads();
  }
  const unsigned T = prefix;
  const int needed = rem;

  const int CH = 10;
  int i0 = t * CH;
  int i1 = i0 + CH; if (i1 > NNODES) i1 = NNODES;
  int loc = 0;
  for (int i = i0; i < i1; ++i)
    loc += ((__float_as_uint(fabsf(s_h[i])) & 0xFFFF0000u) == T) ? 1 : 0;
  int incl = loc;
#pragma unroll
  for (int off = 1; off < 64; off <<= 1) {
    int o = __shfl_up(incl, off);
    if (lane >= off) incl += o;
  }
  if (lane == 63) s_wsum[wid] = incl;
  __syncthreads();
  if (t < 64) {
    int v = (lane < 16) ? s_wsum[lane] : 0;
    int inc16 = v;
#pragma unroll
    for (int off = 1; off < 16; off <<= 1) {
      int o = __shfl_up(inc16, off);
      if (lane >= off) inc16 += o;
    }
    if (lane < 16) s_wpre[lane] = inc16 - v;
  }
  __syncthreads();
  int rank = s_wpre[wid] + (incl - loc);

  float a0 = 0.f, a1 = 0.f;
  for (int i = i0; i < i1; ++i) {
    float h = s_h[i];
    unsigned kp = __float_as_uint(fabsf(h)) & 0xFFFF0000u;
    bool inc = false;
    if (kp > T) inc = true;
    else if (kp == T) { inc = (rank < needed); ++rank; }
    if (inc) {
      a0 += h * fc2w[i];
      a1 += h * fc2w[NNODES + i];
    }
  }
  s_red[t] = a0; __syncthreads();
  for (int off = 512; off > 0; off >>= 1) {
    if (t < off) s_red[t] += s_red[t + off];
    __syncthreads();
  }
  float r0 = s_red[0];
  __syncthreads();
  s_red[t] = a1; __syncthreads();
  for (int off = 512; off > 0; off >>= 1) {
    if (t < off) s_red[t] += s_red[t + off];
    __syncthreads();
  }
  if (t == 0) {
    out[g * 2 + 0] = r0 + fc2b[0];
    out[g * 2 + 1] = s_red[0] + fc2b[1];
  }
}

// ---------------- launch ----------------
extern "C" void kernel_launch(void* const* d_in, const int* in_sizes, int n_in,
                              void* d_out, int out_size, void* d_ws, size_t ws_size,
                              hipStream_t stream) {
  const float* tr  = (const float*)d_in[0];
  const float* x   = (const float*)d_in[1];
  const int*   ei  = (const int*)d_in[2];
  const float* adj = (const float*)d_in[4];
  const float* w1  = (const float*)d_in[5];
  const float* b1  = (const float*)d_in[6];
  const float* wr  = (const float*)d_in[7];
  const float* wn  = (const float*)d_in[8];
  const float* pb  = (const float*)d_in[9];
  const float* w2  = (const float*)d_in[10];
  const float* b2  = (const float*)d_in[11];

  char* ws = (char*)d_ws;
  float* xg       = (float*)ws;                                        // 2.56 MB
  float* partials = (float*)(ws + (size_t)NTOT * 4);                   // 4.10 MB
  int*   part_sum = (int*)(ws + (size_t)NTOT * 4 + (size_t)KSPLIT * 64 * NANNOT * 4);
  int*   part_deg = part_sum + (size_t)4 * NGRAPH * NNODES;            // 10.24 MB each
  float* out = (float*)d_out;

  dim3 g1(NANNOT / 64, KSPLIT);   // 125 x 2 = 250 blocks
  fc1_kernel<<<g1, 256, 0, stream>>>(tr, w1, adj, partials);
  finalize_kernel<<<(NTOT / 4 + 255) / 256, 256, 0, stream>>>(
      (const float4*)partials, b1, (const float4*)x, (float4*)xg);
  agg_kernel<<<4 * NGRAPH, 1024, 0, stream>>>(ei, xg, part_sum, part_deg);
  select_kernel<<<NGRAPH, 1024, 0, stream>>>(part_sum, part_deg, xg, wr, wn, pb, w2, b2, out);
}

// Round 16
// 194.325 us; speedup vs baseline: 1.3018x; 1.2430x over previous
//
#include <hip/hip_runtime.h>
#include <hip/hip_bf16.h>

#define NGRAPH 64
#define NGENES 16000
#define NANNOT 8000
#define NNODES 10000
#define NTOT   (NGRAPH * NNODES)
#define DEG    4
#define NEDGE  (NGRAPH * NNODES * DEG)
#define KSEL   5000
#define FIXS   1048576.0f

#define KSPLIT 2
#define KSTEP  160
#define KSTEPS (NGENES / KSPLIT / KSTEP)   // 50
#define LDSROW 164                         // 160 + 4 pad ushorts (328 B row)

typedef __attribute__((ext_vector_type(8))) short bf16x8;
typedef __attribute__((ext_vector_type(4))) float f32x4;

__device__ __forceinline__ unsigned short f2bf(float x) {
  __hip_bfloat16 h = __float2bfloat16(x);   // RN
  return __builtin_bit_cast(unsigned short, h);
}
__device__ __forceinline__ float bf2f(unsigned short u) {
  unsigned int v = (unsigned int)u << 16;
  return __builtin_bit_cast(float, v);
}

// ---------------- kernel B: masked fc1, bf16x2 MFMA, sparse-w, 8-wave TLP -----------
// 512 threads = 8 waves = 2 waves/SIMD (the r15 kernel ran 4 waves = 1/SIMD and was
// latency-structure-bound, invariant under byte reduction). Wave (mg=wv>>2, ng=wv&3)
// computes the M=32 x N=16 sub-tile; per-element FLOP order unchanged -> bit-identical.
__global__ __launch_bounds__(512, 1) void fc1_kernel(
    const float* __restrict__ tr, const float* __restrict__ w,
    const float* __restrict__ mk, float* __restrict__ partials) {
  __shared__ unsigned short sAh[2][64 * LDSROW];
  __shared__ unsigned short sBh[2][64 * LDSROW];
  __shared__ unsigned short sBl[2][64 * LDSROW];

  const int t = threadIdx.x;
  const int abase = blockIdx.x * 64;                 // 125 * 64 = 8000
  const int kbeg  = blockIdx.y * (NGENES / KSPLIT);  // 0 or 8000
  const int wv = t >> 6, lane = t & 63, lr = lane & 15, ls = lane >> 4;
  const int mg = wv >> 2, ng = wv & 3;

  // staging map: 2560 float4 per (array, step); 5 per thread at 512 threads
  int soff[5], loff[5];
#pragma unroll
  for (int j = 0; j < 5; ++j) {
    int f = t + 512 * j;
    int row = f / 40, c4 = f - 40 * row;
    soff[j] = row * NGENES + c4 * 4;
    loff[j] = row * LDSROW + c4 * 4;
  }
  const float* wB = w  + (size_t)abase * NGENES;
  const float* aB = mk + (size_t)abase * NGENES;

  float4 rtA[5], rwA[5] = {}, rtB[5], rwB[5] = {}, ra[5];
  unsigned nibA, nibB;   // 20 bits: 4 per j

  auto issue_adj = [&](int s) {
    const int k0 = kbeg + s * KSTEP;
#pragma unroll
    for (int j = 0; j < 5; ++j) ra[j] = *(const float4*)&aB[soff[j] + k0];
  };
  auto compress = [&]() -> unsigned {
    unsigned bx = 0;
#pragma unroll
    for (int j = 0; j < 5; ++j) {
      unsigned nb = (ra[j].x != 0.f ? 1u : 0u) | (ra[j].y != 0.f ? 2u : 0u) |
                    (ra[j].z != 0.f ? 4u : 0u) | (ra[j].w != 0.f ? 8u : 0u);
      bx |= nb << (4 * j);
    }
    return bx;
  };
  auto issue_trf = [&](float4* rt, int s) {
    const int k0 = kbeg + s * KSTEP;
#pragma unroll
    for (int j = 0; j < 5; ++j) rt[j] = *(const float4*)&tr[soff[j] + k0];
  };
  auto issue_wf = [&](float4* rw, unsigned nib, int s) {
    const int k0 = kbeg + s * KSTEP;
#pragma unroll
    for (int j = 0; j < 5; ++j)
      if ((nib >> (4 * j)) & 15u) rw[j] = *(const float4*)&wB[soff[j] + k0];
  };
  auto do_store = [&](int buf, float4* rt, float4* rw, unsigned nib) {
#pragma unroll
    for (int j = 0; j < 5; ++j) {
      ushort4 ah;
      ah.x = f2bf(rt[j].x); ah.y = f2bf(rt[j].y);
      ah.z = f2bf(rt[j].z); ah.w = f2bf(rt[j].w);
      *(ushort4*)&sAh[buf][loff[j]] = ah;
      unsigned nb = (nib >> (4 * j)) & 15u;
      float4 p;
      p.x = (nb & 1u) ? rw[j].x : 0.f;
      p.y = (nb & 2u) ? rw[j].y : 0.f;
      p.z = (nb & 4u) ? rw[j].z : 0.f;
      p.w = (nb & 8u) ? rw[j].w : 0.f;
      ushort4 bh, bl;
      bh.x = f2bf(p.x); bl.x = f2bf(p.x - bf2f(bh.x));
      bh.y = f2bf(p.y); bl.y = f2bf(p.y - bf2f(bh.y));
      bh.z = f2bf(p.z); bl.z = f2bf(p.z - bf2f(bh.z));
      bh.w = f2bf(p.w); bl.w = f2bf(p.w - bf2f(bh.w));
      *(ushort4*)&sBh[buf][loff[j]] = bh;
      *(ushort4*)&sBl[buf][loff[j]] = bl;
    }
  };

  f32x4 acc[2];
#pragma unroll
  for (int mt = 0; mt < 2; ++mt)
#pragma unroll
    for (int r = 0; r < 4; ++r) acc[mt][r] = 0.f;

  const int fbA = (mg * 32 + lr) * LDSROW + ls * 8;   // wave's M-half, rows +mt*16
  const int fbB = (ng * 16 + lr) * LDSROW + ls * 8;   // wave's 16-col slice

  auto compute = [&](int buf) {
#pragma unroll
    for (int ks = 0; ks < KSTEP / 32; ++ks) {
      bf16x8 bh = *(const bf16x8*)&sBh[buf][fbB + ks * 32];
      bf16x8 bl = *(const bf16x8*)&sBl[buf][fbB + ks * 32];
#pragma unroll
      for (int mt = 0; mt < 2; ++mt) {
        bf16x8 ah = *(const bf16x8*)&sAh[buf][mt * 16 * LDSROW + fbA + ks * 32];
        acc[mt] = __builtin_amdgcn_mfma_f32_16x16x32_bf16(ah, bh, acc[mt], 0, 0, 0);
        acc[mt] = __builtin_amdgcn_mfma_f32_16x16x32_bf16(ah, bl, acc[mt], 0, 0, 0);
      }
    }
  };

  // ---- prologue: invariant (nibA = bits[s+1]; adj[s+2] in flight) ----
  issue_adj(0);
  nibA = compress();                 // bits[0]
  issue_adj(1);
  issue_trf(rtA, 0); issue_wf(rwA, nibA, 0);
  do_store(0, rtA, rwA, nibA);       // step 0 -> buf0
  nibB = compress();                 // bits[1]
  issue_adj(2);
  issue_trf(rtB, 1); issue_wf(rwB, nibB, 1);
  nibA = nibB;
  __syncthreads();

#pragma unroll 1
  for (int sp = 0; sp < 25; ++sp) {
    const int s = 2 * sp;
    compute(0);                      // step s (buf0)
    do_store(1, rtB, rwB, nibA);     // step s+1 -> buf1
    if (s + 2 < KSTEPS) {
      nibB = compress();             // bits[s+2]
      if (s + 3 < KSTEPS) issue_adj(s + 3);
      issue_wf(rwA, nibB, s + 2);
      issue_trf(rtA, s + 2);
      nibA = nibB;
    }
    __syncthreads();
    compute(1);                      // step s+1 (buf1)
    if (s + 2 < KSTEPS) {
      do_store(0, rtA, rwA, nibA);   // step s+2 -> buf0
      if (s + 3 < KSTEPS) {
        nibB = compress();           // bits[s+3]
        if (s + 4 < KSTEPS) issue_adj(s + 4);
        issue_wf(rwB, nibB, s + 3);
        issue_trf(rtB, s + 3);
        nibA = nibB;
      }
    }
    __syncthreads();
  }

  // epilogue: D col = lane&15, row = (lane>>4)*4 + reg   [m89-verified]
  float* P = partials + (size_t)blockIdx.y * (64 * NANNOT);
  const int acol = abase + ng * 16 + lr;
#pragma unroll
  for (int mt = 0; mt < 2; ++mt) {
#pragma unroll
    for (int r = 0; r < 4; ++r) {
      int b = mg * 32 + mt * 16 + ls * 4 + r;
      P[(size_t)b * NANNOT + acol] = acc[mt][r];
    }
  }
}

// ---------------- kernel B2: finalize xg, float4 (branch uniform per quad) ---------
__global__ void finalize_kernel(const float4* __restrict__ partials4,
                                const float* __restrict__ fc1_b,
                                const float4* __restrict__ x4,
                                float4* __restrict__ xg4) {
  int idx4 = blockIdx.x * blockDim.x + threadIdx.x;
  if (idx4 >= NTOT / 4) return;
  int idx = idx4 * 4;
  int b = idx / NNODES, local = idx - b * NNODES;
  float4 o;
  if (local < NANNOT) {
    int p4 = (b * NANNOT + local) >> 2;
    float4 s0 = partials4[p4];
    float4 s1 = partials4[(64 * NANNOT) / 4 + p4];
    const float4 bb = *(const float4*)&fc1_b[local];
    o = make_float4(bb.x + s0.x + s1.x, bb.y + s0.y + s1.y,
                    bb.z + s0.z + s1.z, bb.w + s0.w + s1.w);
  } else {
    o = x4[idx4];
  }
  xg4[idx4] = o;
}

// ---------------- kernel C1: edge aggregation, 4 blocks/graph, LDS atomics ---------
__global__ __launch_bounds__(1024) void agg_kernel(
    const int* __restrict__ ei, const float* __restrict__ xg,
    int* __restrict__ part_sum, int* __restrict__ part_deg) {
  const int blk = blockIdx.x;          // 0..255
  const int g = blk >> 2, q = blk & 3;
  const int t = threadIdx.x;
  __shared__ int s_sum[NNODES];
  __shared__ int s_deg[NNODES];
  for (int i = t; i < NNODES; i += 1024) { s_sum[i] = 0; s_deg[i] = 0; }
  __syncthreads();

  const int ebase = g * (NNODES * DEG) + q * (NNODES * DEG / 4);
  const int base = g * NNODES;
  const int4* src4 = (const int4*)(ei + ebase);
  const int4* dst4 = (const int4*)(ei + NEDGE + ebase);
  const int nq = (NNODES * DEG / 4) / 4;   // 2500
  for (int v = t; v < nq; v += 1024) {
    int4 s4 = src4[v];
    int4 d4 = dst4[v];
#pragma unroll
    for (int u = 0; u < 4; ++u) {
      int s = (&s4.x)[u];
      int d = (&d4.x)[u];
      float vv = ((unsigned)s < (unsigned)NTOT) ? xg[s] : 0.f;
      unsigned dl = (unsigned)(d - base);
      if (dl < (unsigned)NNODES) {
        atomicAdd(&s_sum[dl], __float2int_rn(vv * FIXS));
        atomicAdd(&s_deg[dl], 1);
      }
    }
  }
  __syncthreads();

  int* ps = part_sum + (size_t)blk * NNODES;
  int* pd = part_deg + (size_t)blk * NNODES;
  for (int i = t; i < NNODES; i += 1024) { ps[i] = s_sum[i]; pd[i] = s_deg[i]; }
}

// ---------------- kernel C2: per-graph h + 2-pass radix select + fc2 ---------------
__global__ __launch_bounds__(1024) void select_kernel(
    const int* __restrict__ part_sum, const int* __restrict__ part_deg,
    const float* __restrict__ xg,
    const float* __restrict__ wrp, const float* __restrict__ wnp,
    const float* __restrict__ pbp, const float* __restrict__ fc2w,
    const float* __restrict__ fc2b, float* __restrict__ out) {
  const int g = blockIdx.x;
  const int t = threadIdx.x;
  const int lane = t & 63, wid = t >> 6;
  __shared__ float s_h[NNODES];
  __shared__ int s_hist[256];
  __shared__ int s_cnt[256];
  __shared__ float s_red[1024];
  __shared__ int s_wsum[16];
  __shared__ int s_wpre[16];
  __shared__ unsigned s_pfx;
  __shared__ int s_rem;

  const int base = g * NNODES;
  const float wr = wrp[0], wn = wnp[0], pb = pbp[0];
  for (int i = t; i < NNODES; i += 1024) {
    int sum = 0, dg = 0;
#pragma unroll
    for (int q = 0; q < 4; ++q) {
      size_t off = (size_t)(g * 4 + q) * NNODES + i;
      sum += part_sum[off];
      dg  += part_deg[off];
    }
    float mean = ((float)sum * (1.0f / FIXS)) / (float)(dg > 0 ? dg : 1);
    s_h[i] = wr * xg[base + i] + wn * mean + pb;
  }
  __syncthreads();

  // 2-pass radix: top-16-bit prefix T; rank-gate prefix-ties (lowest index first)
  unsigned prefix = 0; int rem = KSEL;
#pragma unroll
  for (int pass = 0; pass < 2; ++pass) {
    const int sh = (3 - pass) * 8;
    const unsigned himask = (pass == 0) ? 0u : 0xFF000000u;
    if (t < 256) s_hist[t] = 0;
    __syncthreads();
    for (int i = t; i < NNODES; i += 1024) {
      unsigned kk = __float_as_uint(fabsf(s_h[i]));
      if ((kk & himask) == prefix) atomicAdd(&s_hist[(kk >> sh) & 255], 1);
    }
    __syncthreads();
    if (wid == 0) {
      int h0 = s_hist[4 * lane], h1 = s_hist[4 * lane + 1];
      int h2 = s_hist[4 * lane + 2], h3 = s_hist[4 * lane + 3];
      int lt = h0 + h1 + h2 + h3;
      int sfx = lt;
#pragma unroll
      for (int off = 1; off < 64; off <<= 1) {
        int o = __shfl_down(sfx, off);
        sfx += (lane + off < 64) ? o : 0;
      }
      int above = sfx - lt;
      int ge3 = above + h3;
      int ge2 = ge3 + h2;
      int ge1 = ge2 + h1;
      int ge0 = ge1 + h0;
      s_cnt[4 * lane]     = ge0;
      s_cnt[4 * lane + 1] = ge1;
      s_cnt[4 * lane + 2] = ge2;
      s_cnt[4 * lane + 3] = ge3;
    }
    __syncthreads();
    if (t < 256) {
      int ge = s_cnt[t];
      int ge_next = (t == 255) ? 0 : s_cnt[t + 1];
      if (ge >= rem && ge_next < rem) {
        s_pfx = prefix | ((unsigned)t << sh);
        s_rem = rem - ge_next;
      }
    }
    __syncthreads();
    prefix = s_pfx; rem = s_rem;
    __syncthreads();
  }
  const unsigned T = prefix;
  const int needed = rem;

  const int CH = 10;
  int i0 = t * CH;
  int i1 = i0 + CH; if (i1 > NNODES) i1 = NNODES;
  int loc = 0;
  for (int i = i0; i < i1; ++i)
    loc += ((__float_as_uint(fabsf(s_h[i])) & 0xFFFF0000u) == T) ? 1 : 0;
  int incl = loc;
#pragma unroll
  for (int off = 1; off < 64; off <<= 1) {
    int o = __shfl_up(incl, off);
    if (lane >= off) incl += o;
  }
  if (lane == 63) s_wsum[wid] = incl;
  __syncthreads();
  if (t < 64) {
    int v = (lane < 16) ? s_wsum[lane] : 0;
    int inc16 = v;
#pragma unroll
    for (int off = 1; off < 16; off <<= 1) {
      int o = __shfl_up(inc16, off);
      if (lane >= off) inc16 += o;
    }
    if (lane < 16) s_wpre[lane] = inc16 - v;
  }
  __syncthreads();
  int rank = s_wpre[wid] + (incl - loc);

  float a0 = 0.f, a1 = 0.f;
  for (int i = i0; i < i1; ++i) {
    float h = s_h[i];
    unsigned kp = __float_as_uint(fabsf(h)) & 0xFFFF0000u;
    bool inc = false;
    if (kp > T) inc = true;
    else if (kp == T) { inc = (rank < needed); ++rank; }
    if (inc) {
      a0 += h * fc2w[i];
      a1 += h * fc2w[NNODES + i];
    }
  }
  s_red[t] = a0; __syncthreads();
  for (int off = 512; off > 0; off >>= 1) {
    if (t < off) s_red[t] += s_red[t + off];
    __syncthreads();
  }
  float r0 = s_red[0];
  __syncthreads();
  s_red[t] = a1; __syncthreads();
  for (int off = 512; off > 0; off >>= 1) {
    if (t < off) s_red[t] += s_red[t + off];
    __syncthreads();
  }
  if (t == 0) {
    out[g * 2 + 0] = r0 + fc2b[0];
    out[g * 2 + 1] = s_red[0] + fc2b[1];
  }
}

// ---------------- launch ----------------
extern "C" void kernel_launch(void* const* d_in, const int* in_sizes, int n_in,
                              void* d_out, int out_size, void* d_ws, size_t ws_size,
                              hipStream_t stream) {
  const float* tr  = (const float*)d_in[0];
  const float* x   = (const float*)d_in[1];
  const int*   ei  = (const int*)d_in[2];
  const float* adj = (const float*)d_in[4];
  const float* w1  = (const float*)d_in[5];
  const float* b1  = (const float*)d_in[6];
  const float* wr  = (const float*)d_in[7];
  const float* wn  = (const float*)d_in[8];
  const float* pb  = (const float*)d_in[9];
  const float* w2  = (const float*)d_in[10];
  const float* b2  = (const float*)d_in[11];

  char* ws = (char*)d_ws;
  float* xg       = (float*)ws;                                        // 2.56 MB
  float* partials = (float*)(ws + (size_t)NTOT * 4);                   // 4.10 MB
  int*   part_sum = (int*)(ws + (size_t)NTOT * 4 + (size_t)KSPLIT * 64 * NANNOT * 4);
  int*   part_deg = part_sum + (size_t)4 * NGRAPH * NNODES;            // 10.24 MB each
  float* out = (float*)d_out;

  dim3 g1(NANNOT / 64, KSPLIT);   // 125 x 2 = 250 blocks
  fc1_kernel<<<g1, 512, 0, stream>>>(tr, w1, adj, partials);
  finalize_kernel<<<(NTOT / 4 + 255) / 256, 256, 0, stream>>>(
      (const float4*)partials, b1, (const float4*)x, (float4*)xg);
  agg_kernel<<<4 * NGRAPH, 1024, 0, stream>>>(ei, xg, part_sum, part_deg);
  select_kernel<<<NGRAPH, 1024, 0, stream>>>(part_sum, part_deg, xg, wr, wn, pb, w2, b2, out);
}

// Round 17
// 178.264 us; speedup vs baseline: 1.4191x; 1.0901x over previous
//
#include <hip/hip_runtime.h>
#include <hip/hip_bf16.h>

#define NGRAPH 64
#define NGENES 16000
#define NANNOT 8000
#define NNODES 10000
#define NTOT   (NGRAPH * NNODES)
#define DEG    4
#define NEDGE  (NGRAPH * NNODES * DEG)
#define KSEL   5000
#define FIXS   1048576.0f

#define KSPLIT 2
#define KSTEP  160
#define KSTEPS (NGENES / KSPLIT / KSTEP)   // 50
#define LDSROW 164                         // 160 + 4 pad ushorts (328 B row)

typedef __attribute__((ext_vector_type(8))) short bf16x8;
typedef __attribute__((ext_vector_type(4))) float f32x4;

__device__ __forceinline__ unsigned short f2bf(float x) {
  __hip_bfloat16 h = __float2bfloat16(x);   // RN
  return __builtin_bit_cast(unsigned short, h);
}
__device__ __forceinline__ float bf2f(unsigned short u) {
  unsigned int v = (unsigned int)u << 16;
  return __builtin_bit_cast(float, v);
}

// ---------------- kernel B: masked fc1, bf16x2 MFMA, sparse-w, 16-wave TLP ----------
// 1024 threads = 16 waves = 4 waves/SIMD (r16's 2/SIMD cut fc1 187->140; latency still
// exposed). Wave (mg,ng) in 4x4 computes a 16x16 sub-tile. Staging: threads<512 take a
// 3rd float4 (2560/1024=2.5); guard is wave-uniform. Bit-identical to r12/r15/r16.
__global__ __launch_bounds__(1024, 1) void fc1_kernel(
    const float* __restrict__ tr, const float* __restrict__ w,
    const float* __restrict__ mk, float* __restrict__ partials) {
  __shared__ unsigned short sAh[2][64 * LDSROW];
  __shared__ unsigned short sBh[2][64 * LDSROW];
  __shared__ unsigned short sBl[2][64 * LDSROW];

  const int t = threadIdx.x;
  const int abase = blockIdx.x * 64;                 // 125 * 64 = 8000
  const int kbeg  = blockIdx.y * (NGENES / KSPLIT);  // 0 or 8000
  const int wv = t >> 6, lane = t & 63, lr = lane & 15, ls = lane >> 4;
  const int mg = wv >> 2, ng = wv & 3;
  const bool third = (t < 512);                      // wave-uniform

  // staging map: 2560 float4 per (array, step); 2 per thread + 1 extra for t<512
  int soff[3], loff[3];
#pragma unroll
  for (int j = 0; j < 3; ++j) {
    int f = (j == 2) ? (third ? t + 2048 : t) : (t + 1024 * j);
    int row = f / 40, c4 = f - 40 * row;
    soff[j] = row * NGENES + c4 * 4;
    loff[j] = row * LDSROW + c4 * 4;
  }
  const float* wB = w  + (size_t)abase * NGENES;
  const float* aB = mk + (size_t)abase * NGENES;

  float4 rtA[3], rwA[3] = {}, rtB[3], rwB[3] = {}, ra[3];
  unsigned nibA, nibB;   // 12 bits used: 4 per j

  auto issue_adj = [&](int s) {
    const int k0 = kbeg + s * KSTEP;
#pragma unroll
    for (int j = 0; j < 3; ++j)
      if (j < 2 || third) ra[j] = *(const float4*)&aB[soff[j] + k0];
  };
  auto compress = [&]() -> unsigned {
    unsigned bx = 0;
#pragma unroll
    for (int j = 0; j < 3; ++j) {
      if (j < 2 || third) {
        unsigned nb = (ra[j].x != 0.f ? 1u : 0u) | (ra[j].y != 0.f ? 2u : 0u) |
                      (ra[j].z != 0.f ? 4u : 0u) | (ra[j].w != 0.f ? 8u : 0u);
        bx |= nb << (4 * j);
      }
    }
    return bx;
  };
  auto issue_trf = [&](float4* rt, int s) {
    const int k0 = kbeg + s * KSTEP;
#pragma unroll
    for (int j = 0; j < 3; ++j)
      if (j < 2 || third) rt[j] = *(const float4*)&tr[soff[j] + k0];
  };
  auto issue_wf = [&](float4* rw, unsigned nib, int s) {
    const int k0 = kbeg + s * KSTEP;
#pragma unroll
    for (int j = 0; j < 3; ++j)
      if ((j < 2 || third) && ((nib >> (4 * j)) & 15u))
        rw[j] = *(const float4*)&wB[soff[j] + k0];
  };
  auto do_store = [&](int buf, float4* rt, float4* rw, unsigned nib) {
#pragma unroll
    for (int j = 0; j < 3; ++j) {
      if (j < 2 || third) {
        ushort4 ah;
        ah.x = f2bf(rt[j].x); ah.y = f2bf(rt[j].y);
        ah.z = f2bf(rt[j].z); ah.w = f2bf(rt[j].w);
        *(ushort4*)&sAh[buf][loff[j]] = ah;
        unsigned nb = (nib >> (4 * j)) & 15u;
        float4 p;
        p.x = (nb & 1u) ? rw[j].x : 0.f;
        p.y = (nb & 2u) ? rw[j].y : 0.f;
        p.z = (nb & 4u) ? rw[j].z : 0.f;
        p.w = (nb & 8u) ? rw[j].w : 0.f;
        ushort4 bh, bl;
        bh.x = f2bf(p.x); bl.x = f2bf(p.x - bf2f(bh.x));
        bh.y = f2bf(p.y); bl.y = f2bf(p.y - bf2f(bh.y));
        bh.z = f2bf(p.z); bl.z = f2bf(p.z - bf2f(bh.z));
        bh.w = f2bf(p.w); bl.w = f2bf(p.w - bf2f(bh.w));
        *(ushort4*)&sBh[buf][loff[j]] = bh;
        *(ushort4*)&sBl[buf][loff[j]] = bl;
      }
    }
  };

  f32x4 acc;
#pragma unroll
  for (int r = 0; r < 4; ++r) acc[r] = 0.f;

  const int fbA = (mg * 16 + lr) * LDSROW + ls * 8;   // wave's 16 M-rows
  const int fbB = (ng * 16 + lr) * LDSROW + ls * 8;   // wave's 16 N-cols

  auto compute = [&](int buf) {
#pragma unroll
    for (int ks = 0; ks < KSTEP / 32; ++ks) {
      bf16x8 bh = *(const bf16x8*)&sBh[buf][fbB + ks * 32];
      bf16x8 bl = *(const bf16x8*)&sBl[buf][fbB + ks * 32];
      bf16x8 ah = *(const bf16x8*)&sAh[buf][fbA + ks * 32];
      acc = __builtin_amdgcn_mfma_f32_16x16x32_bf16(ah, bh, acc, 0, 0, 0);
      acc = __builtin_amdgcn_mfma_f32_16x16x32_bf16(ah, bl, acc, 0, 0, 0);
    }
  };

  // ---- prologue: invariant (nibA = bits[s+1]; adj[s+2] in flight) ----
  issue_adj(0);
  nibA = compress();                 // bits[0]
  issue_adj(1);
  issue_trf(rtA, 0); issue_wf(rwA, nibA, 0);
  do_store(0, rtA, rwA, nibA);       // step 0 -> buf0
  nibB = compress();                 // bits[1]
  issue_adj(2);
  issue_trf(rtB, 1); issue_wf(rwB, nibB, 1);
  nibA = nibB;
  __syncthreads();

#pragma unroll 1
  for (int sp = 0; sp < 25; ++sp) {
    const int s = 2 * sp;
    compute(0);                      // step s (buf0)
    do_store(1, rtB, rwB, nibA);     // step s+1 -> buf1
    if (s + 2 < KSTEPS) {
      nibB = compress();             // bits[s+2]
      if (s + 3 < KSTEPS) issue_adj(s + 3);
      issue_wf(rwA, nibB, s + 2);
      issue_trf(rtA, s + 2);
      nibA = nibB;
    }
    __syncthreads();
    compute(1);                      // step s+1 (buf1)
    if (s + 2 < KSTEPS) {
      do_store(0, rtA, rwA, nibA);   // step s+2 -> buf0
      if (s + 3 < KSTEPS) {
        nibB = compress();           // bits[s+3]
        if (s + 4 < KSTEPS) issue_adj(s + 4);
        issue_wf(rwB, nibB, s + 3);
        issue_trf(rtB, s + 3);
        nibA = nibB;
      }
    }
    __syncthreads();
  }

  // epilogue: D col = lane&15, row = (lane>>4)*4 + reg   [m89-verified]
  float* P = partials + (size_t)blockIdx.y * (64 * NANNOT);
  const int acol = abase + ng * 16 + lr;
#pragma unroll
  for (int r = 0; r < 4; ++r) {
    int b = mg * 16 + ls * 4 + r;
    P[(size_t)b * NANNOT + acol] = acc[r];
  }
}

// ---------------- kernel B2: finalize xg, float4 (branch uniform per quad) ---------
__global__ void finalize_kernel(const float4* __restrict__ partials4,
                                const float* __restrict__ fc1_b,
                                const float4* __restrict__ x4,
                                float4* __restrict__ xg4) {
  int idx4 = blockIdx.x * blockDim.x + threadIdx.x;
  if (idx4 >= NTOT / 4) return;
  int idx = idx4 * 4;
  int b = idx / NNODES, local = idx - b * NNODES;
  float4 o;
  if (local < NANNOT) {
    int p4 = (b * NANNOT + local) >> 2;
    float4 s0 = partials4[p4];
    float4 s1 = partials4[(64 * NANNOT) / 4 + p4];
    const float4 bb = *(const float4*)&fc1_b[local];
    o = make_float4(bb.x + s0.x + s1.x, bb.y + s0.y + s1.y,
                    bb.z + s0.z + s1.z, bb.w + s0.w + s1.w);
  } else {
    o = x4[idx4];
  }
  xg4[idx4] = o;
}

// ---------------- kernel C1: edge aggregation, 4 blocks/graph, LDS atomics ---------
__global__ __launch_bounds__(1024) void agg_kernel(
    const int* __restrict__ ei, const float* __restrict__ xg,
    int* __restrict__ part_sum, int* __restrict__ part_deg) {
  const int blk = blockIdx.x;          // 0..255
  const int g = blk >> 2, q = blk & 3;
  const int t = threadIdx.x;
  __shared__ int s_sum[NNODES];
  __shared__ int s_deg[NNODES];
  for (int i = t; i < NNODES; i += 1024) { s_sum[i] = 0; s_deg[i] = 0; }
  __syncthreads();

  const int ebase = g * (NNODES * DEG) + q * (NNODES * DEG / 4);
  const int base = g * NNODES;
  const int4* src4 = (const int4*)(ei + ebase);
  const int4* dst4 = (const int4*)(ei + NEDGE + ebase);
  const int nq = (NNODES * DEG / 4) / 4;   // 2500
  for (int v = t; v < nq; v += 1024) {
    int4 s4 = src4[v];
    int4 d4 = dst4[v];
#pragma unroll
    for (int u = 0; u < 4; ++u) {
      int s = (&s4.x)[u];
      int d = (&d4.x)[u];
      float vv = ((unsigned)s < (unsigned)NTOT) ? xg[s] : 0.f;
      unsigned dl = (unsigned)(d - base);
      if (dl < (unsigned)NNODES) {
        atomicAdd(&s_sum[dl], __float2int_rn(vv * FIXS));
        atomicAdd(&s_deg[dl], 1);
      }
    }
  }
  __syncthreads();

  int* ps = part_sum + (size_t)blk * NNODES;
  int* pd = part_deg + (size_t)blk * NNODES;
  for (int i = t; i < NNODES; i += 1024) { ps[i] = s_sum[i]; pd[i] = s_deg[i]; }
}

// ---------------- kernel C2: per-graph h + 2-pass radix select + fc2 ---------------
__global__ __launch_bounds__(1024) void select_kernel(
    const int* __restrict__ part_sum, const int* __restrict__ part_deg,
    const float* __restrict__ xg,
    const float* __restrict__ wrp, const float* __restrict__ wnp,
    const float* __restrict__ pbp, const float* __restrict__ fc2w,
    const float* __restrict__ fc2b, float* __restrict__ out) {
  const int g = blockIdx.x;
  const int t = threadIdx.x;
  const int lane = t & 63, wid = t >> 6;
  __shared__ float s_h[NNODES];
  __shared__ int s_hist[256];
  __shared__ int s_cnt[256];
  __shared__ float s_red[1024];
  __shared__ int s_wsum[16];
  __shared__ int s_wpre[16];
  __shared__ unsigned s_pfx;
  __shared__ int s_rem;

  const int base = g * NNODES;
  const float wr = wrp[0], wn = wnp[0], pb = pbp[0];
  for (int i = t; i < NNODES; i += 1024) {
    int sum = 0, dg = 0;
#pragma unroll
    for (int q = 0; q < 4; ++q) {
      size_t off = (size_t)(g * 4 + q) * NNODES + i;
      sum += part_sum[off];
      dg  += part_deg[off];
    }
    float mean = ((float)sum * (1.0f / FIXS)) / (float)(dg > 0 ? dg : 1);
    s_h[i] = wr * xg[base + i] + wn * mean + pb;
  }
  __syncthreads();

  // 2-pass radix: top-16-bit prefix T; rank-gate prefix-ties (lowest index first)
  unsigned prefix = 0; int rem = KSEL;
#pragma unroll
  for (int pass = 0; pass < 2; ++pass) {
    const int sh = (3 - pass) * 8;
    const unsigned himask = (pass == 0) ? 0u : 0xFF000000u;
    if (t < 256) s_hist[t] = 0;
    __syncthreads();
    for (int i = t; i < NNODES; i += 1024) {
      unsigned kk = __float_as_uint(fabsf(s_h[i]));
      if ((kk & himask) == prefix) atomicAdd(&s_hist[(kk >> sh) & 255], 1);
    }
    __syncthreads();
    if (wid == 0) {
      int h0 = s_hist[4 * lane], h1 = s_hist[4 * lane + 1];
      int h2 = s_hist[4 * lane + 2], h3 = s_hist[4 * lane + 3];
      int lt = h0 + h1 + h2 + h3;
      int sfx = lt;
#pragma unroll
      for (int off = 1; off < 64; off <<= 1) {
        int o = __shfl_down(sfx, off);
        sfx += (lane + off < 64) ? o : 0;
      }
      int above = sfx - lt;
      int ge3 = above + h3;
      int ge2 = ge3 + h2;
      int ge1 = ge2 + h1;
      int ge0 = ge1 + h0;
      s_cnt[4 * lane]     = ge0;
      s_cnt[4 * lane + 1] = ge1;
      s_cnt[4 * lane + 2] = ge2;
      s_cnt[4 * lane + 3] = ge3;
    }
    __syncthreads();
    if (t < 256) {
      int ge = s_cnt[t];
      int ge_next = (t == 255) ? 0 : s_cnt[t + 1];
      if (ge >= rem && ge_next < rem) {
        s_pfx = prefix | ((unsigned)t << sh);
        s_rem = rem - ge_next;
      }
    }
    __syncthreads();
    prefix = s_pfx; rem = s_rem;
    __syncthreads();
  }
  const unsigned T = prefix;
  const int needed = rem;

  const int CH = 10;
  int i0 = t * CH;
  int i1 = i0 + CH; if (i1 > NNODES) i1 = NNODES;
  int loc = 0;
  for (int i = i0; i < i1; ++i)
    loc += ((__float_as_uint(fabsf(s_h[i])) & 0xFFFF0000u) == T) ? 1 : 0;
  int incl = loc;
#pragma unroll
  for (int off = 1; off < 64; off <<= 1) {
    int o = __shfl_up(incl, off);
    if (lane >= off) incl += o;
  }
  if (lane == 63) s_wsum[wid] = incl;
  __syncthreads();
  if (t < 64) {
    int v = (lane < 16) ? s_wsum[lane] : 0;
    int inc16 = v;
#pragma unroll
    for (int off = 1; off < 16; off <<= 1) {
      int o = __shfl_up(inc16, off);
      if (lane >= off) inc16 += o;
    }
    if (lane < 16) s_wpre[lane] = inc16 - v;
  }
  __syncthreads();
  int rank = s_wpre[wid] + (incl - loc);

  float a0 = 0.f, a1 = 0.f;
  for (int i = i0; i < i1; ++i) {
    float h = s_h[i];
    unsigned kp = __float_as_uint(fabsf(h)) & 0xFFFF0000u;
    bool inc = false;
    if (kp > T) inc = true;
    else if (kp == T) { inc = (rank < needed); ++rank; }
    if (inc) {
      a0 += h * fc2w[i];
      a1 += h * fc2w[NNODES + i];
    }
  }
  s_red[t] = a0; __syncthreads();
  for (int off = 512; off > 0; off >>= 1) {
    if (t < off) s_red[t] += s_red[t + off];
    __syncthreads();
  }
  float r0 = s_red[0];
  __syncthreads();
  s_red[t] = a1; __syncthreads();
  for (int off = 512; off > 0; off >>= 1) {
    if (t < off) s_red[t] += s_red[t + off];
    __syncthreads();
  }
  if (t == 0) {
    out[g * 2 + 0] = r0 + fc2b[0];
    out[g * 2 + 1] = s_red[0] + fc2b[1];
  }
}

// ---------------- launch ----------------
extern "C" void kernel_launch(void* const* d_in, const int* in_sizes, int n_in,
                              void* d_out, int out_size, void* d_ws, size_t ws_size,
                              hipStream_t stream) {
  const float* tr  = (const float*)d_in[0];
  const float* x   = (const float*)d_in[1];
  const int*   ei  = (const int*)d_in[2];
  const float* adj = (const float*)d_in[4];
  const float* w1  = (const float*)d_in[5];
  const float* b1  = (const float*)d_in[6];
  const float* wr  = (const float*)d_in[7];
  const float* wn  = (const float*)d_in[8];
  const float* pb  = (const float*)d_in[9];
  const float* w2  = (const float*)d_in[10];
  const float* b2  = (const float*)d_in[11];

  char* ws = (char*)d_ws;
  float* xg       = (float*)ws;                                        // 2.56 MB
  float* partials = (float*)(ws + (size_t)NTOT * 4);                   // 4.10 MB
  int*   part_sum = (int*)(ws + (size_t)NTOT * 4 + (size_t)KSPLIT * 64 * NANNOT * 4);
  int*   part_deg = part_sum + (size_t)4 * NGRAPH * NNODES;            // 10.24 MB each
  float* out = (float*)d_out;

  dim3 g1(NANNOT / 64, KSPLIT);   // 125 x 2 = 250 blocks
  fc1_kernel<<<g1, 1024, 0, stream>>>(tr, w1, adj, partials);
  finalize_kernel<<<(NTOT / 4 + 255) / 256, 256, 0, stream>>>(
      (const float4*)partials, b1, (const float4*)x, (float4*)xg);
  agg_kernel<<<4 * NGRAPH, 1024, 0, stream>>>(ei, xg, part_sum, part_deg);
  select_kernel<<<NGRAPH, 1024, 0, stream>>>(part_sum, part_deg, xg, wr, wn, pb, w2, b2, out);
}